// Round 15
// baseline (599.100 us; speedup 1.0000x reference)
//
#include <hip/hip_runtime.h>
#include <stdint.h>

#define N_NODES 50000
#define N_EDGES 800000
#define IN_C 64
#define HID 128
#define OUT_C 2
#define N_GRAPHS 64
#define NBUCK 196                    // ceil(N_NODES/256) buckets of 256 nodes
#define BCAP 6144                    // bucket capacity (mean 4096, sd ~64)
#define MECH 3125                    // edges per binA chunk (800000/256)
#define MCHUNK 256                   // binA chunks
#define NTILE 782                    // ceil(N_NODES/64)
#define GRID 256                     // persistent grid: 1 block/CU guaranteed
#define TPB 1024

typedef long long i64;
typedef __attribute__((ext_vector_type(8))) short bf8;    // 8 bf16 = 4 VGPRs
typedef __attribute__((ext_vector_type(4))) float f32x4;  // MFMA C/D frag

__device__ __forceinline__ float bf2f(ushort h) {
    return __uint_as_float(((uint)h) << 16);
}
__device__ __forceinline__ ushort f2bf(float f) {
    uint x = __float_as_uint(f);
    uint r = x + 0x7fffu + ((x >> 16) & 1u);   // RNE
    return (ushort)(r >> 16);
}
__device__ __forceinline__ float loadf(const void* p, size_t i, int bf) {
    return bf ? bf2f(((const ushort*)p)[i]) : ((const float*)p)[i];
}
__device__ __forceinline__ int clampi(int v, int lo, int hi) {
    return min(max(v, lo), hi);
}

__device__ __forceinline__ int edge_src(const void* ei, int e, int wide) {
    return wide ? (int)((const i64*)ei)[e] : ((const int*)ei)[e];
}
__device__ __forceinline__ int edge_dst(const void* ei, int e, int wide) {
    return wide ? (int)((const i64*)ei)[N_EDGES + e] : ((const int*)ei)[N_EDGES + e];
}
__device__ __forceinline__ i64 batch_at(const void* b, int i, int wide) {
    return wide ? ((const i64*)b)[i] : (i64)((const int*)b)[i];
}

// ---- manual grid barrier: agent-scope fence + per-phase arrival counter.
// Same sequence cooperative grid.sync() lowers to; works in graph capture
// because launches are plain <<<>>>. Counters zeroed by k_prep; each used
// once per launch (no reset race). Bounded spin -> fails visibly, no hang.
__device__ __forceinline__ void gbar(int* __restrict__ bars, int idx) {
    __syncthreads();
    if (threadIdx.x == 0) {
        __threadfence();   // agent release: our global writes visible device-wide
        __hip_atomic_fetch_add(&bars[idx], 1, __ATOMIC_ACQ_REL,
                               __HIP_MEMORY_SCOPE_AGENT);
        long long spin = 0;
        while (__hip_atomic_load(&bars[idx], __ATOMIC_ACQUIRE,
                                 __HIP_MEMORY_SCOPE_AGENT) < GRID) {
            __builtin_amdgcn_s_sleep(8);
            if (++spin > 2000000) break;   // ~0.5s: fail visibly, never hang
        }
    }
    __syncthreads();
}

// ---- prep: zero barrier counters, bcnt, gbuf; block 0 probes dtypes ----
__global__ __launch_bounds__(256) void k_prep(const uint* __restrict__ braw,
                                              const uint* __restrict__ xraw,
                                              int* __restrict__ bars,
                                              int* __restrict__ bcnt,
                                              float* __restrict__ gbuf,
                                              int* __restrict__ iflag,
                                              int* __restrict__ fflag) {
    int i = blockIdx.x * blockDim.x + threadIdx.x;
    if (i < 16) bars[i] = 0;
    if (i < NBUCK) bcnt[i] = 0;
    if (i < N_GRAPHS * HID) gbuf[i] = 0.f;
    if (blockIdx.x == 0) {
        __shared__ uint si[128];
        __shared__ int sf[256];
        int t = threadIdx.x;
        if (t < 128) si[t] = (t < 100) ? braw[25001 + 2 * t] : 0u;
        uint e = (xraw[t] >> 7) & 0xFFu;
        sf[t] = (e >= 100u && e <= 140u) ? 1 : 0;
        __syncthreads();
        for (int off = 128; off > 0; off >>= 1) {
            if (t < off) {
                sf[t] += sf[t + off];
                if (off <= 64 && t < 64) si[t] |= si[t + off];
            }
            __syncthreads();
        }
        if (t == 0) {
            *iflag = (si[0] == 0u) ? 1 : 0;   // 1 = int64, 0 = int32
            *fflag = (sf[0] >= 192) ? 1 : 0;  // 1 = bf16,  0 = f32
        }
    }
}

// =================== persistent mega kernel (manual barriers) ===============

struct SmA {   // binA: chunk histogram + staging (25 KB stage)
    int cnt[NBUCK]; int obase[NBUCK]; int run[NBUCK]; int gbase[NBUCK];
    int sc[256]; uint2 stage[MECH];
};
struct SmB {   // binB: bucket counting-sort
    int sc[256]; int degl[256]; int run[256]; float sdinv[256];
    int sbase, scnt; int stage[BCAP];
};
struct SmP {   // gemm_pool: one 64x128 f32 tile
    float sacc[64][HID]; int sbg[64];
};
struct SmM {   // mlp: 8 graph-groups
    float sg[8][HID]; float r0[8][HID]; float r1[8][HID];
};
union MegaSm { SmA a; SmB b; SmP p; SmM m; };

__global__ __launch_bounds__(TPB) void k_mega(
    const void* __restrict__ x, const void* __restrict__ ei,
    const void* __restrict__ batch,
    const void* __restrict__ W1, const void* __restrict__ b1,
    const void* __restrict__ W2, const void* __restrict__ b2,
    const void* __restrict__ Wm1, const void* __restrict__ bm1,
    const void* __restrict__ Wm2, const void* __restrict__ bm2,
    int* __restrict__ bars, int* __restrict__ bcnt, uint2* __restrict__ bmem,
    float* __restrict__ dinv, int* __restrict__ offs, int* __restrict__ csr,
    ushort* __restrict__ Wt1, ushort* __restrict__ Wt2,
    ushort* __restrict__ Y1, ushort* __restrict__ Mbuf,
    ushort* __restrict__ h1s, ushort* __restrict__ N2,
    float* __restrict__ gbuf, const int* __restrict__ iflag,
    const int* __restrict__ fflag, float* __restrict__ outp) {
    __shared__ MegaSm sm;
    int tid = threadIdx.x;
    int gsz = gridDim.x;

    // ---- P1: binA (edge binning) + weight transpose ----
    {
        int ff = *fflag;
        for (int w = blockIdx.x; w < 24; w += gsz) {
            int idx = w * 1024 + tid;
            if (idx < IN_C * HID) {
                int k = idx >> 7, n = idx & 127;
                Wt1[n * IN_C + k] = f2bf(loadf(W1, idx, ff));
            } else if (idx < IN_C * HID + HID * HID) {
                int j = idx - IN_C * HID;
                int k = j >> 7, n = j & 127;
                Wt2[n * HID + k] = f2bf(loadf(W2, j, ff));
            }
        }
        int wide = *iflag;
        for (int ch = blockIdx.x; ch < MCHUNK; ch += gsz) {
            int e0 = ch * MECH;
            __syncthreads();
            for (int i = tid; i < NBUCK; i += TPB) sm.a.cnt[i] = 0;
            __syncthreads();
            for (int i = tid; i < MECH; i += TPB) {
                int d = edge_dst(ei, e0 + i, wide);
                atomicAdd(&sm.a.cnt[d >> 8], 1);
            }
            __syncthreads();
            int cv = (tid < NBUCK) ? sm.a.cnt[tid] : 0;
            if (tid < 256) sm.a.sc[tid] = cv;
            __syncthreads();
            for (int off = 1; off < 256; off <<= 1) {
                int v = (tid >= off && tid < 256) ? sm.a.sc[tid - off] : 0;
                __syncthreads();
                if (tid < 256) sm.a.sc[tid] += v;
                __syncthreads();
            }
            if (tid < NBUCK) {
                int ex = sm.a.sc[tid] - cv;
                sm.a.obase[tid] = ex;
                sm.a.run[tid] = ex;
                sm.a.gbase[tid] = (cv > 0) ? atomicAdd(&bcnt[tid], cv) : 0;
            }
            __syncthreads();
            for (int i = tid; i < MECH; i += TPB) {
                int s = edge_src(ei, e0 + i, wide);
                int d = edge_dst(ei, e0 + i, wide);
                int slot = atomicAdd(&sm.a.run[d >> 8], 1);
                uint2 pr; pr.x = (uint)s; pr.y = (uint)d;
                sm.a.stage[slot] = pr;
            }
            __syncthreads();
            for (int i = tid; i < MECH; i += TPB) {
                uint2 pr = sm.a.stage[i];
                int b = (int)(pr.y >> 8);
                int pos = sm.a.gbase[b] + (i - sm.a.obase[b]);
                if (pos < BCAP) bmem[(size_t)b * BCAP + pos] = pr;
            }
        }
    }
    gbar(bars, 0);

    // ---- P2: binB (per-bucket counting sort -> offs/csr/dinv/Y1) ----
    {
        int ff = *fflag;
        for (int bk = blockIdx.x; bk < NBUCK; bk += gsz) {
            int node0 = bk << 8;
            __syncthreads();
            int v = (tid < NBUCK) ? bcnt[tid] : 0;
            if (tid < 256) sm.b.sc[tid] = v;
            __syncthreads();
            for (int off = 1; off < 256; off <<= 1) {
                int u = (tid >= off && tid < 256) ? sm.b.sc[tid - off] : 0;
                __syncthreads();
                if (tid < 256) sm.b.sc[tid] += u;
                __syncthreads();
            }
            if (tid == bk) {
                int c = clampi(v, 0, BCAP);
                sm.b.scnt = c;
                sm.b.sbase = clampi(sm.b.sc[tid] - v, 0, N_EDGES - c);
            }
            if (tid < 256) sm.b.degl[tid] = 0;
            __syncthreads();
            int cnt = sm.b.scnt;
            int base = sm.b.sbase;
            for (int i = tid; i < cnt; i += TPB) {
                uint2 pr = bmem[(size_t)bk * BCAP + i];
                atomicAdd(&sm.b.degl[pr.y & 255], 1);
            }
            __syncthreads();
            int dv = (tid < 256) ? sm.b.degl[tid] : 0;
            if (tid < 256) sm.b.sc[tid] = dv;
            __syncthreads();
            for (int off = 1; off < 256; off <<= 1) {
                int u = (tid >= off && tid < 256) ? sm.b.sc[tid - off] : 0;
                __syncthreads();
                if (tid < 256) sm.b.sc[tid] += u;
                __syncthreads();
            }
            if (tid < 256) {
                int ex = sm.b.sc[tid] - dv;
                sm.b.run[tid] = ex;
                float di = rsqrtf((float)(dv + 1));
                sm.b.sdinv[tid] = di;
                int n = node0 + tid;
                if (n < N_NODES) { offs[n] = base + ex; dinv[n] = di; }
            }
            if (bk == 0 && tid == 0) offs[N_NODES] = N_EDGES;
            __syncthreads();
            for (int i = tid; i < cnt; i += TPB) {
                uint2 pr = bmem[(size_t)bk * BCAP + i];
                int slot = atomicAdd(&sm.b.run[pr.y & 255], 1);
                sm.b.stage[clampi(slot, 0, BCAP - 1)] = (int)pr.x;
            }
            __syncthreads();
            for (int i = tid; i < cnt; i += TPB) csr[base + i] = sm.b.stage[i];
            for (int idx = tid; idx < 256 * (IN_C / 4); idx += TPB) {
                int nl = idx >> 4, c4 = (idx & 15) * 4;
                int nn = node0 + nl;
                if (nn < N_NODES) {
                    float x0, x1, x2, x3;
                    if (ff) {
                        ushort4 u = *(const ushort4*)((const ushort*)x + (size_t)nn * IN_C + c4);
                        x0 = bf2f(u.x); x1 = bf2f(u.y); x2 = bf2f(u.z); x3 = bf2f(u.w);
                    } else {
                        float4 vv = *(const float4*)((const float*)x + (size_t)nn * IN_C + c4);
                        x0 = vv.x; x1 = vv.y; x2 = vv.z; x3 = vv.w;
                    }
                    float di = sm.b.sdinv[nl];
                    ushort4 o;
                    o.x = f2bf(x0 * di); o.y = f2bf(x1 * di);
                    o.z = f2bf(x2 * di); o.w = f2bf(x3 * di);
                    *(ushort4*)(Y1 + (size_t)nn * IN_C + c4) = o;
                }
            }
        }
    }
    gbar(bars, 1);

    // ---- P3: aggM (layer-1 gather, 4 nodes/wave) ----
    {
        int g = blockIdx.x * TPB + tid;
        int lane = g & 15;
        int step = (gsz * TPB) >> 4;
        const uint* y32 = (const uint*)Y1;
        for (int n = g >> 4; n < N_NODES; n += step) {
            size_t rb = (size_t)n * 32;
            uint s0 = y32[rb + lane];
            uint s1 = y32[rb + lane + 16];
            float a0 = bf2f((ushort)(s0 & 0xffffu));
            float a1 = bf2f((ushort)(s0 >> 16));
            float a2 = bf2f((ushort)(s1 & 0xffffu));
            float a3 = bf2f((ushort)(s1 >> 16));
            int s = offs[n];
            int e = min(offs[n + 1], s + 4096);
            int i = s;
            for (; i + 8 <= e; i += 8) {
                uint u0[8], u1[8];
#pragma unroll
                for (int k = 0; k < 8; k++) {
                    size_t r = (size_t)csr[i + k] * 32;
                    u0[k] = y32[r + lane];
                    u1[k] = y32[r + lane + 16];
                }
#pragma unroll
                for (int k = 0; k < 8; k++) {
                    a0 += bf2f((ushort)(u0[k] & 0xffffu));
                    a1 += bf2f((ushort)(u0[k] >> 16));
                    a2 += bf2f((ushort)(u1[k] & 0xffffu));
                    a3 += bf2f((ushort)(u1[k] >> 16));
                }
            }
            for (; i < e; i++) {
                size_t r = (size_t)csr[i] * 32;
                uint u0 = y32[r + lane];
                uint u1 = y32[r + lane + 16];
                a0 += bf2f((ushort)(u0 & 0xffffu));
                a1 += bf2f((ushort)(u0 >> 16));
                a2 += bf2f((ushort)(u1 & 0xffffu));
                a3 += bf2f((ushort)(u1 >> 16));
            }
            float dvv = dinv[n];
            ((uint*)Mbuf)[rb + lane] = ((uint)f2bf(a1 * dvv) << 16) | (uint)f2bf(a0 * dvv);
            ((uint*)Mbuf)[rb + lane + 16] = ((uint)f2bf(a3 * dvv) << 16) | (uint)f2bf(a2 * dvv);
        }
    }
    gbar(bars, 2);

    // ---- P4: gemm layer 1 (4 tiles/block via 4-wave groups, no LDS) ----
    {
        int ff = *fflag;
        int group = tid >> 8;
        int subwave = (tid & 255) >> 6;
        int lane = tid & 63;
        int m16 = lane & 15, q = lane >> 4;
        for (int tb = blockIdx.x * 4 + group; tb < NTILE; tb += gsz * 4) {
            int rowbase = tb * 64 + subwave * 16;
            int arow = min(rowbase + m16, N_NODES - 1);
            f32x4 acc[8];
#pragma unroll
            for (int t = 0; t < 8; t++) acc[t] = (f32x4){0.f, 0.f, 0.f, 0.f};
#pragma unroll
            for (int kc = 0; kc < IN_C; kc += 32) {
                bf8 a = *(const bf8*)(Mbuf + (size_t)arow * IN_C + kc + q * 8);
#pragma unroll
                for (int t = 0; t < 8; t++) {
                    bf8 b = *(const bf8*)(Wt1 + (size_t)(t * 16 + m16) * IN_C + kc + q * 8);
                    acc[t] = __builtin_amdgcn_mfma_f32_16x16x32_bf16(a, b, acc[t], 0, 0, 0);
                }
            }
            float dvr[4];
            int rowok[4];
#pragma unroll
            for (int r = 0; r < 4; r++) {
                int row = rowbase + q * 4 + r;
                rowok[r] = (row < N_NODES);
                dvr[r] = rowok[r] ? dinv[row] : 1.f;
            }
#pragma unroll
            for (int t = 0; t < 8; t++) {
                int col = t * 16 + m16;
                float bv = loadf(b1, col, ff);
#pragma unroll
                for (int r = 0; r < 4; r++) {
                    int row = rowbase + q * 4 + r;
                    if (rowok[r]) {
                        float v = fmaxf(acc[t][r] + bv, 0.f) * dvr[r];
                        h1s[(size_t)row * HID + col] = f2bf(v);
                    }
                }
            }
        }
    }
    gbar(bars, 3);

    // ---- P5: agg128 (layer-2 gather, 2 nodes/wave) ----
    {
        int g = blockIdx.x * TPB + tid;
        int lane = g & 31;
        int step = (gsz * TPB) >> 5;
        const uint* hs32 = (const uint*)h1s;
        for (int n = g >> 5; n < N_NODES; n += step) {
            size_t rb = (size_t)n * 64;
            uint s0 = hs32[rb + lane];
            uint s1 = hs32[rb + lane + 32];
            float a0 = bf2f((ushort)(s0 & 0xffffu));
            float a1 = bf2f((ushort)(s0 >> 16));
            float a2 = bf2f((ushort)(s1 & 0xffffu));
            float a3 = bf2f((ushort)(s1 >> 16));
            int s = offs[n];
            int e = min(offs[n + 1], s + 4096);
            int i = s;
            for (; i + 8 <= e; i += 8) {
                uint u0[8], u1[8];
#pragma unroll
                for (int k = 0; k < 8; k++) {
                    size_t r = (size_t)csr[i + k] * 64;
                    u0[k] = hs32[r + lane];
                    u1[k] = hs32[r + lane + 32];
                }
#pragma unroll
                for (int k = 0; k < 8; k++) {
                    a0 += bf2f((ushort)(u0[k] & 0xffffu));
                    a1 += bf2f((ushort)(u0[k] >> 16));
                    a2 += bf2f((ushort)(u1[k] & 0xffffu));
                    a3 += bf2f((ushort)(u1[k] >> 16));
                }
            }
            for (; i < e; i++) {
                size_t r = (size_t)csr[i] * 64;
                uint u0 = hs32[r + lane];
                uint u1 = hs32[r + lane + 32];
                a0 += bf2f((ushort)(u0 & 0xffffu));
                a1 += bf2f((ushort)(u0 >> 16));
                a2 += bf2f((ushort)(u1 & 0xffffu));
                a3 += bf2f((ushort)(u1 >> 16));
            }
            float dvv = dinv[n];
            ((uint*)N2)[rb + lane] = ((uint)f2bf(a1 * dvv) << 16) | (uint)f2bf(a0 * dvv);
            ((uint*)N2)[rb + lane + 32] = ((uint)f2bf(a3 * dvv) << 16) | (uint)f2bf(a2 * dvv);
        }
    }
    gbar(bars, 4);

    // ---- P6: gemm layer 2 + fused mean-pool (16 waves, K-split tile) ----
    {
        int wide = *iflag;
        int wave = tid >> 6;
        int strip = wave & 3;     // 16-row strip
        int ksl = wave >> 2;      // K slice (32 wide)
        int lane = tid & 63;
        int m16 = lane & 15, q = lane >> 4;
        for (int tile = blockIdx.x; tile < NTILE; tile += gsz) {
            for (int i = tid; i < 64 * HID; i += TPB) ((float*)sm.p.sacc)[i] = 0.f;
            if (tid < 64) {
                int n = tile * 64 + tid;
                int g = (n < N_NODES) ? (int)batch_at(batch, n, wide) : -1;
                sm.p.sbg[tid] = (g < 0 || g >= N_GRAPHS) ? -1 : g;
            }
            __syncthreads();
            int rowbase = tile * 64 + strip * 16;
            int arow = min(rowbase + m16, N_NODES - 1);
            int kc = ksl * 32;
            f32x4 acc[8];
#pragma unroll
            for (int t = 0; t < 8; t++) acc[t] = (f32x4){0.f, 0.f, 0.f, 0.f};
            bf8 a = *(const bf8*)(N2 + (size_t)arow * HID + kc + q * 8);
#pragma unroll
            for (int t = 0; t < 8; t++) {
                bf8 b = *(const bf8*)(Wt2 + (size_t)(t * 16 + m16) * HID + kc + q * 8);
                acc[t] = __builtin_amdgcn_mfma_f32_16x16x32_bf16(a, b, acc[t], 0, 0, 0);
            }
#pragma unroll
            for (int t = 0; t < 8; t++) {
                int col = t * 16 + m16;
#pragma unroll
                for (int r = 0; r < 4; r++) {
                    int rl = strip * 16 + q * 4 + r;
                    int row = rowbase + q * 4 + r;
                    if (row < N_NODES) atomicAdd(&sm.p.sacc[rl][col], acc[t][r]);
                }
            }
            __syncthreads();
            int col = tid & 127;
            int rc = tid >> 7;    // 8 row-chunks of 8 rows
            int gcur = -1;
            float aa = 0.f;
            for (int r = rc * 8; r < rc * 8 + 8; r++) {
                int g = sm.p.sbg[r];
                if (g != gcur) {
                    if (gcur >= 0) atomicAdd(&gbuf[gcur * HID + col], aa);
                    aa = 0.f;
                    gcur = g;
                }
                aa += sm.p.sacc[r][col];
            }
            if (gcur >= 0) atomicAdd(&gbuf[gcur * HID + col], aa);
            __syncthreads();
        }
    }
    gbar(bars, 5);

    // ---- P7: MLP head (blocks 0..7, 8 graphs each) ----
    {
        int ff = *fflag;
        int wide = *iflag;
        int group = tid >> 7;
        int c = tid & 127;
        int gr = blockIdx.x * 8 + group;
        bool act = (gr < N_GRAPHS);
        if (blockIdx.x * 8 < N_GRAPHS) {
            if (act) {
                int lo = 0, hi = N_NODES;
                while (lo < hi) { int m = (lo + hi) >> 1; if (batch_at(batch, m, wide) < (i64)gr) lo = m + 1; else hi = m; }
                int s = lo;
                lo = s; hi = N_NODES;
                while (lo < hi) { int m = (lo + hi) >> 1; if (batch_at(batch, m, wide) < (i64)(gr + 1)) lo = m + 1; else hi = m; }
                float cntf = fmaxf((float)(lo - s), 1.0f);
                sm.m.sg[group][c] = gbuf[gr * HID + c] / cntf + loadf(b2, c, ff);
            }
            __syncthreads();
            if (act) {
                float acc = loadf(bm1, c, ff);
#pragma unroll 8
                for (int k = 0; k < HID; k++) acc += sm.m.sg[group][k] * loadf(Wm1, k * HID + c, ff);
                float hid = fmaxf(acc, 0.f);
                sm.m.r0[group][c] = hid * loadf(Wm2, c * OUT_C + 0, ff);
                sm.m.r1[group][c] = hid * loadf(Wm2, c * OUT_C + 1, ff);
            }
            __syncthreads();
            for (int off = 64; off > 0; off >>= 1) {
                if (act && c < off) {
                    sm.m.r0[group][c] += sm.m.r0[group][c + off];
                    sm.m.r1[group][c] += sm.m.r1[group][c + off];
                }
                __syncthreads();
            }
            if (act && c == 0) {
                outp[gr * OUT_C + 0] = sm.m.r0[group][0] + loadf(bm2, 0, ff);
                outp[gr * OUT_C + 1] = sm.m.r1[group][0] + loadf(bm2, 1, ff);
            }
        }
    }
}

// ---------------- launch ----------------

extern "C" void kernel_launch(void* const* d_in, const int* in_sizes, int n_in,
                              void* d_out, int out_size, void* d_ws, size_t ws_size,
                              hipStream_t stream) {
    const void* x     = d_in[0];
    const void* ei    = d_in[1];
    const void* batch = d_in[2];
    const void* W1  = d_in[3];
    const void* b1  = d_in[4];
    const void* W2  = d_in[5];
    const void* b2  = d_in[6];
    const void* Wm1 = d_in[7];
    const void* bm1 = d_in[8];
    const void* Wm2 = d_in[9];
    const void* bm2 = d_in[10];

    char* p = (char*)d_ws;
    auto alloc = [&](size_t bytes) {
        char* r = p;
        p += (bytes + 255) & ~(size_t)255;
        return r;
    };
    int*    bars   = (int*)alloc(16 * 4);
    int*    iflag  = (int*)alloc(4);
    int*    fflag  = (int*)alloc(4);
    int*    bcnt   = (int*)alloc(NBUCK * 4);
    uint2*  bmem   = (uint2*)alloc((size_t)NBUCK * BCAP * 8);
    float*  dinv   = (float*)alloc(N_NODES * 4);
    int*    offs   = (int*)alloc((N_NODES + 1) * 4);
    int*    csr    = (int*)alloc(N_EDGES * 4);
    ushort* Wt1    = (ushort*)alloc(IN_C * HID * 2);
    ushort* Wt2    = (ushort*)alloc(HID * HID * 2);
    ushort* Y1     = (ushort*)alloc((size_t)N_NODES * IN_C * 2);
    ushort* Mbuf   = (ushort*)alloc((size_t)N_NODES * IN_C * 2);
    ushort* h1s    = (ushort*)alloc((size_t)N_NODES * HID * 2);
    ushort* N2     = (ushort*)alloc((size_t)N_NODES * HID * 2);
    float*  gbuf   = (float*)alloc(N_GRAPHS * HID * 4);
    float*  outp   = (float*)d_out;

    k_prep<<<(N_GRAPHS * HID + 255) / 256, 256, 0, stream>>>(
        (const uint*)batch, (const uint*)x, bars, bcnt, gbuf, iflag, fflag);
    k_mega<<<GRID, TPB, 0, stream>>>(
        x, ei, batch, W1, b1, W2, b2, Wm1, bm1, Wm2, bm2,
        bars, bcnt, bmem, dinv, offs, csr, Wt1, Wt2, Y1, Mbuf,
        h1s, N2, gbuf, iflag, fflag, outp);
}

// Round 16
// 199.675 us; speedup vs baseline: 3.0004x; 3.0004x over previous
//
#include <hip/hip_runtime.h>
#include <stdint.h>

#define N_NODES 50000
#define N_EDGES 800000
#define IN_C 64
#define HID 128
#define OUT_C 2
#define N_GRAPHS 64
#define NBUCK 196                    // ceil(N_NODES/256) buckets of 256 nodes
#define BCAP 6144                    // bucket capacity (mean 4096, sd ~64)
#define ECH 4096                     // edges per phase-A block

typedef long long i64;
typedef __attribute__((ext_vector_type(8))) short bf8;    // 8 bf16 = 4 VGPRs
typedef __attribute__((ext_vector_type(4))) float f32x4;  // MFMA C/D frag

__device__ __forceinline__ float bf2f(ushort h) {
    return __uint_as_float(((uint)h) << 16);
}
__device__ __forceinline__ ushort f2bf(float f) {
    uint x = __float_as_uint(f);
    uint r = x + 0x7fffu + ((x >> 16) & 1u);   // RNE
    return (ushort)(r >> 16);
}
__device__ __forceinline__ float loadf(const void* p, size_t i, int bf) {
    return bf ? bf2f(((const ushort*)p)[i]) : ((const float*)p)[i];
}
__device__ __forceinline__ int clampi(int v, int lo, int hi) {
    return min(max(v, lo), hi);
}

__device__ __forceinline__ int edge_src(const void* ei, int e, int wide) {
    return wide ? (int)((const i64*)ei)[e] : ((const int*)ei)[e];
}
__device__ __forceinline__ int edge_dst(const void* ei, int e, int wide) {
    return wide ? (int)((const i64*)ei)[N_EDGES + e] : ((const int*)ei)[N_EDGES + e];
}
__device__ __forceinline__ i64 batch_at(const void* b, int i, int wide) {
    return wide ? ((const i64*)b)[i] : (i64)((const int*)b)[i];
}

// ---- init: zero bcnt/gbuf; block 0 also runs the dtype probes ----
__global__ __launch_bounds__(256) void k_init(const uint* __restrict__ braw,
                                              const uint* __restrict__ xraw,
                                              int* __restrict__ bcnt,
                                              float* __restrict__ gbuf,
                                              int* __restrict__ iflag,
                                              int* __restrict__ fflag) {
    int i = blockIdx.x * blockDim.x + threadIdx.x;
    if (i < N_GRAPHS * HID) gbuf[i] = 0.f;
    if (i < NBUCK) bcnt[i] = 0;
    if (blockIdx.x == 0) {
        __shared__ uint si[128];
        __shared__ int sf[256];
        int t = threadIdx.x;
        if (t < 128) si[t] = (t < 100) ? braw[25001 + 2 * t] : 0u;
        uint e = (xraw[t] >> 7) & 0xFFu;
        sf[t] = (e >= 100u && e <= 140u) ? 1 : 0;
        __syncthreads();
        for (int off = 128; off > 0; off >>= 1) {
            if (t < off) {
                sf[t] += sf[t + off];
                if (off <= 64 && t < 64) si[t] |= si[t + off];
            }
            __syncthreads();
        }
        if (t == 0) {
            *iflag = (si[0] == 0u) ? 1 : 0;   // 1 = int64, 0 = int32
            *fflag = (sf[0] >= 192) ? 1 : 0;  // 1 = bf16,  0 = f32
        }
    }
}

// ---- phase A: bin edges by dst>>8 via LDS-sorted staging; contiguous runs.
// 1024 threads/block. Threads t<256 of blocks 0..95 also transpose W1/W2. ----
__global__ __launch_bounds__(1024) void k_binA(const void* __restrict__ ei,
                                               const int* __restrict__ iflag,
                                               const int* __restrict__ fflag,
                                               const void* __restrict__ W1,
                                               const void* __restrict__ W2,
                                               ushort* __restrict__ Wt1,
                                               ushort* __restrict__ Wt2,
                                               int* __restrict__ bcnt,
                                               uint2* __restrict__ bmem) {
    int t = threadIdx.x;
    if (t < 256 && blockIdx.x < (IN_C * HID + HID * HID) / 256) {
        int ff = *fflag;
        int idx = blockIdx.x * 256 + t;
        if (idx < IN_C * HID) {
            int k = idx >> 7, n = idx & 127;
            Wt1[n * IN_C + k] = f2bf(loadf(W1, idx, ff));
        } else {
            int j = idx - IN_C * HID;
            int k = j >> 7, n = j & 127;
            Wt2[n * HID + k] = f2bf(loadf(W2, j, ff));
        }
    }
    int wide = *iflag;
    __shared__ int cnt[NBUCK];
    __shared__ int obase[NBUCK];
    __shared__ int run[NBUCK];
    __shared__ int gbase[NBUCK];
    __shared__ int sc[256];
    __shared__ uint2 stage[ECH];
    int e0 = blockIdx.x * ECH;
    int m = min(ECH, N_EDGES - e0);
    for (int i = t; i < NBUCK; i += 1024) cnt[i] = 0;
    __syncthreads();
    for (int i = t; i < m; i += 1024) {
        int d = edge_dst(ei, e0 + i, wide);
        atomicAdd(&cnt[d >> 8], 1);
    }
    __syncthreads();
    int cv = (t < NBUCK) ? cnt[t] : 0;
    if (t < 256) sc[t] = cv;
    __syncthreads();
    for (int off = 1; off < 256; off <<= 1) {
        int v = (t >= off && t < 256) ? sc[t - off] : 0;
        __syncthreads();
        if (t < 256) sc[t] += v;
        __syncthreads();
    }
    if (t < NBUCK) {
        int ex = sc[t] - cv;
        obase[t] = ex;
        run[t] = ex;
        gbase[t] = (cv > 0) ? atomicAdd(&bcnt[t], cv) : 0;
    }
    __syncthreads();
    for (int i = t; i < m; i += 1024) {
        int s = edge_src(ei, e0 + i, wide);
        int d = edge_dst(ei, e0 + i, wide);
        int slot = atomicAdd(&run[d >> 8], 1);
        uint2 pr; pr.x = (uint)s; pr.y = (uint)d;
        stage[slot] = pr;
    }
    __syncthreads();
    for (int i = t; i < m; i += 1024) {
        uint2 pr = stage[i];
        int b = (int)(pr.y >> 8);
        int pos = gbase[b] + (i - obase[b]);
        if (pos < BCAP) bmem[(size_t)b * BCAP + pos] = pr;
    }
}

// ---- phase B: per-bucket LDS counting-sort -> offs/csr/dinv (coalesced),
// self-scans bcnt, writes Y1 = bf16(dinv * x) with vector IO. 1024 thr. ----
__global__ __launch_bounds__(1024) void k_binB(const uint2* __restrict__ bmem,
                                               const int* __restrict__ bcnt,
                                               const void* __restrict__ x,
                                               const int* __restrict__ fflag,
                                               int* __restrict__ offs,
                                               int* __restrict__ csr,
                                               float* __restrict__ dinv,
                                               ushort* __restrict__ Y1) {
    int b = blockIdx.x;
    int t = threadIdx.x;
    int node0 = b << 8;
    __shared__ int sc[256];
    __shared__ int degl[256];
    __shared__ int run[256];
    __shared__ float sdinv[256];
    __shared__ int sbase, scnt;
    __shared__ int stage[BCAP];
    int v = (t < NBUCK) ? bcnt[t] : 0;
    if (t < 256) sc[t] = v;
    __syncthreads();
    for (int off = 1; off < 256; off <<= 1) {
        int u = (t >= off && t < 256) ? sc[t - off] : 0;
        __syncthreads();
        if (t < 256) sc[t] += u;
        __syncthreads();
    }
    if (t == b) {
        int c = clampi(v, 0, BCAP);
        scnt = c;
        sbase = clampi(sc[t] - v, 0, N_EDGES - c);
    }
    if (t < 256) degl[t] = 0;
    __syncthreads();
    int cnt = scnt;
    int base = sbase;
    for (int i = t; i < cnt; i += 1024) {
        uint2 pr = bmem[(size_t)b * BCAP + i];
        atomicAdd(&degl[pr.y & 255], 1);
    }
    __syncthreads();
    int dv = (t < 256) ? degl[t] : 0;
    if (t < 256) sc[t] = dv;
    __syncthreads();
    for (int off = 1; off < 256; off <<= 1) {
        int u = (t >= off && t < 256) ? sc[t - off] : 0;
        __syncthreads();
        if (t < 256) sc[t] += u;
        __syncthreads();
    }
    if (t < 256) {
        int ex = sc[t] - dv;
        run[t] = ex;
        float di = rsqrtf((float)(dv + 1));
        sdinv[t] = di;
        int n = node0 + t;
        if (n < N_NODES) { offs[n] = base + ex; dinv[n] = di; }
    }
    if (b == 0 && t == 0) offs[N_NODES] = N_EDGES;
    __syncthreads();
    for (int i = t; i < cnt; i += 1024) {
        uint2 pr = bmem[(size_t)b * BCAP + i];
        int slot = atomicAdd(&run[pr.y & 255], 1);
        stage[clampi(slot, 0, BCAP - 1)] = (int)pr.x;
    }
    __syncthreads();
    for (int i = t; i < cnt; i += 1024) csr[base + i] = stage[i];
    int ff = *fflag;
    for (int idx = t; idx < 256 * (IN_C / 4); idx += 1024) {
        int nl = idx >> 4, c4 = (idx & 15) * 4;
        int nn = node0 + nl;
        if (nn < N_NODES) {
            float x0, x1, x2, x3;
            if (ff) {
                ushort4 u = *(const ushort4*)((const ushort*)x + (size_t)nn * IN_C + c4);
                x0 = bf2f(u.x); x1 = bf2f(u.y); x2 = bf2f(u.z); x3 = bf2f(u.w);
            } else {
                float4 vv = *(const float4*)((const float*)x + (size_t)nn * IN_C + c4);
                x0 = vv.x; x1 = vv.y; x2 = vv.z; x3 = vv.w;
            }
            float di = sdinv[nl];
            ushort4 o;
            o.x = f2bf(x0 * di); o.y = f2bf(x1 * di);
            o.z = f2bf(x2 * di); o.w = f2bf(x3 * di);
            *(ushort4*)(Y1 + (size_t)nn * IN_C + c4) = o;
        }
    }
}

// ---- layer-1 gather: M[n] = bf16(dinv[n]*(sum Y1[src]+Y1[n])), 64 ch.
// R16: 8 nodes/wave (8 lanes/node, 4 u32/lane) -> 2x outstanding loads. ----
__global__ __launch_bounds__(256) void k_aggM(const ushort* __restrict__ Y1,
                                              const float* __restrict__ dinv,
                                              const int* __restrict__ offs,
                                              const int* __restrict__ csr,
                                              ushort* __restrict__ M) {
    int n = (blockIdx.x * blockDim.x + threadIdx.x) >> 3;
    int lane = threadIdx.x & 7;
    if (n >= N_NODES) return;
    const uint* y32 = (const uint*)Y1;
    size_t rb = (size_t)n * 32;
    float a[8];
#pragma unroll
    for (int j = 0; j < 4; j++) {
        uint u = y32[rb + lane + 8 * j];
        a[2 * j] = bf2f((ushort)(u & 0xffffu));
        a[2 * j + 1] = bf2f((ushort)(u >> 16));
    }
    int s = offs[n];
    int e = min(offs[n + 1], s + 4096);   // poison-replay guard
    int i = s;
    for (; i + 8 <= e; i += 8) {
        uint u[8][4];
#pragma unroll
        for (int k = 0; k < 8; k++) {
            size_t r = (size_t)csr[i + k] * 32;
#pragma unroll
            for (int j = 0; j < 4; j++) u[k][j] = y32[r + lane + 8 * j];
        }
#pragma unroll
        for (int k = 0; k < 8; k++) {
#pragma unroll
            for (int j = 0; j < 4; j++) {
                a[2 * j] += bf2f((ushort)(u[k][j] & 0xffffu));
                a[2 * j + 1] += bf2f((ushort)(u[k][j] >> 16));
            }
        }
    }
    for (; i < e; i++) {
        size_t r = (size_t)csr[i] * 32;
#pragma unroll
        for (int j = 0; j < 4; j++) {
            uint u = y32[r + lane + 8 * j];
            a[2 * j] += bf2f((ushort)(u & 0xffffu));
            a[2 * j + 1] += bf2f((ushort)(u >> 16));
        }
    }
    float dv = dinv[n];
#pragma unroll
    for (int j = 0; j < 4; j++) {
        ((uint*)M)[rb + lane + 8 * j] =
            ((uint)f2bf(a[2 * j + 1] * dv) << 16) | (uint)f2bf(a[2 * j] * dv);
    }
}

// ---- layer-2 gather: N2[n] = bf16(dinv[n]*(sum h1s[src]+h1s[n])), 128 ch.
// R16: 4 nodes/wave (16 lanes/node, 4 u32/lane) -> 2x outstanding loads. ----
__global__ __launch_bounds__(256) void k_agg128(const ushort* __restrict__ hs,
                                                const float* __restrict__ dinv,
                                                const int* __restrict__ offs,
                                                const int* __restrict__ csr,
                                                ushort* __restrict__ out) {
    int n = (blockIdx.x * blockDim.x + threadIdx.x) >> 4;
    int lane = threadIdx.x & 15;
    if (n >= N_NODES) return;
    const uint* hs32 = (const uint*)hs;
    size_t rb = (size_t)n * 64;
    float a[8];
#pragma unroll
    for (int j = 0; j < 4; j++) {
        uint u = hs32[rb + lane + 16 * j];
        a[2 * j] = bf2f((ushort)(u & 0xffffu));
        a[2 * j + 1] = bf2f((ushort)(u >> 16));
    }
    int s = offs[n];
    int e = min(offs[n + 1], s + 4096);   // poison-replay guard
    int i = s;
    for (; i + 8 <= e; i += 8) {
        uint u[8][4];
#pragma unroll
        for (int k = 0; k < 8; k++) {
            size_t r = (size_t)csr[i + k] * 64;
#pragma unroll
            for (int j = 0; j < 4; j++) u[k][j] = hs32[r + lane + 16 * j];
        }
#pragma unroll
        for (int k = 0; k < 8; k++) {
#pragma unroll
            for (int j = 0; j < 4; j++) {
                a[2 * j] += bf2f((ushort)(u[k][j] & 0xffffu));
                a[2 * j + 1] += bf2f((ushort)(u[k][j] >> 16));
            }
        }
    }
    for (; i < e; i++) {
        size_t r = (size_t)csr[i] * 64;
#pragma unroll
        for (int j = 0; j < 4; j++) {
            uint u = hs32[r + lane + 16 * j];
            a[2 * j] += bf2f((ushort)(u & 0xffffu));
            a[2 * j + 1] += bf2f((ushort)(u >> 16));
        }
    }
    float dv = dinv[n];
#pragma unroll
    for (int j = 0; j < 4; j++) {
        ((uint*)out)[rb + lane + 16 * j] =
            ((uint)f2bf(a[2 * j + 1] * dv) << 16) | (uint)f2bf(a[2 * j] * dv);
    }
}

// ------- MFMA GEMM layer 1: h1s = bf16(relu(M@W1 + b1) * dinv) -------------
template <int K>
__global__ __launch_bounds__(256) void k_gemm_f(const ushort* __restrict__ A,
                                                const ushort* __restrict__ Wt,
                                                const int* __restrict__ fflag,
                                                const float* __restrict__ dinv,
                                                const void* __restrict__ bias,
                                                ushort* __restrict__ out) {
    int ff = *fflag;
    int wave = threadIdx.x >> 6;
    int lane = threadIdx.x & 63;
    int m16 = lane & 15;
    int q = lane >> 4;
    int rowbase = blockIdx.x * 64 + wave * 16;
    int arow = min(rowbase + m16, N_NODES - 1);

    f32x4 acc[8];
#pragma unroll
    for (int t = 0; t < 8; t++) acc[t] = (f32x4){0.f, 0.f, 0.f, 0.f};
#pragma unroll
    for (int kc = 0; kc < K; kc += 32) {
        bf8 a = *(const bf8*)(A + (size_t)arow * K + kc + q * 8);
#pragma unroll
        for (int t = 0; t < 8; t++) {
            bf8 b = *(const bf8*)(Wt + (size_t)(t * 16 + m16) * K + kc + q * 8);
            acc[t] = __builtin_amdgcn_mfma_f32_16x16x32_bf16(a, b, acc[t], 0, 0, 0);
        }
    }
    float dv[4];
    int rowok[4];
#pragma unroll
    for (int r = 0; r < 4; r++) {
        int row = rowbase + q * 4 + r;
        rowok[r] = (row < N_NODES);
        dv[r] = rowok[r] ? dinv[row] : 1.f;
    }
#pragma unroll
    for (int t = 0; t < 8; t++) {
        int col = t * 16 + m16;
        float bv = loadf(bias, col, ff);
#pragma unroll
        for (int r = 0; r < 4; r++) {
            int row = rowbase + q * 4 + r;
            if (rowok[r]) {
                float v = fmaxf(acc[t][r] + bv, 0.f) * dv[r];
                out[(size_t)row * HID + col] = f2bf(v);
            }
        }
    }
}

// ------- MFMA GEMM layer 2 + fused mean-pool (bias deferred to MLP) --------
__global__ __launch_bounds__(256) void k_gemm_pool(const ushort* __restrict__ A,
                                                   const ushort* __restrict__ Wt,
                                                   const void* __restrict__ batch,
                                                   const int* __restrict__ iflag,
                                                   float* __restrict__ gsum) {
    const int K = HID;
    int wide = *iflag;
    int tid = threadIdx.x;
    int wave = tid >> 6;
    int lane = tid & 63;
    int m16 = lane & 15;
    int q = lane >> 4;
    int rowbase = blockIdx.x * 64 + wave * 16;
    int arow = min(rowbase + m16, N_NODES - 1);

    __shared__ float sacc[64][HID];
    __shared__ int sbg[64];

    if (tid < 64) {
        int n = blockIdx.x * 64 + tid;
        int g = (n < N_NODES) ? (int)batch_at(batch, n, wide) : -1;
        sbg[tid] = (g < 0 || g >= N_GRAPHS) ? -1 : g;
    }
    f32x4 acc[8];
#pragma unroll
    for (int t = 0; t < 8; t++) acc[t] = (f32x4){0.f, 0.f, 0.f, 0.f};
#pragma unroll
    for (int kc = 0; kc < K; kc += 32) {
        bf8 a = *(const bf8*)(A + (size_t)arow * K + kc + q * 8);
#pragma unroll
        for (int t = 0; t < 8; t++) {
            bf8 b = *(const bf8*)(Wt + (size_t)(t * 16 + m16) * K + kc + q * 8);
            acc[t] = __builtin_amdgcn_mfma_f32_16x16x32_bf16(a, b, acc[t], 0, 0, 0);
        }
    }
#pragma unroll
    for (int t = 0; t < 8; t++) {
        int col = t * 16 + m16;
#pragma unroll
        for (int r = 0; r < 4; r++) {
            int rl = wave * 16 + q * 4 + r;
            int row = rowbase + q * 4 + r;
            sacc[rl][col] = (row < N_NODES) ? acc[t][r] : 0.f;
        }
    }
    __syncthreads();
    int col = tid & 127;
    int half = tid >> 7;
    int gcur = -1;
    float a = 0.f;
    for (int r = half * 32; r < half * 32 + 32; r++) {
        int g = sbg[r];
        if (g != gcur) {
            if (gcur >= 0) atomicAdd(&gsum[gcur * HID + col], a);
            a = 0.f;
            gcur = g;
        }
        a += sacc[r][col];
    }
    if (gcur >= 0) atomicAdd(&gsum[gcur * HID + col], a);
}

// -------- MLP head: out = relu((gsum/cnt + b2)@Wm1+bm1)@Wm2 + bm2 ; f32 -----
__global__ void k_mlp(const float* __restrict__ gsum, const void* __restrict__ batch,
                      const int* __restrict__ iflag, const void* __restrict__ b2,
                      const void* __restrict__ Wm1, const void* __restrict__ bm1,
                      const void* __restrict__ Wm2, const void* __restrict__ bm2,
                      const int* __restrict__ fflag, float* __restrict__ out) {
    int ff = *fflag;
    int wide = *iflag;
    int gr = blockIdx.x;
    int c = threadIdx.x;
    int lo = 0, hi = N_NODES;
    while (lo < hi) { int m = (lo + hi) >> 1; if (batch_at(batch, m, wide) < (i64)gr) lo = m + 1; else hi = m; }
    int s = lo;
    lo = s; hi = N_NODES;
    while (lo < hi) { int m = (lo + hi) >> 1; if (batch_at(batch, m, wide) < (i64)(gr + 1)) lo = m + 1; else hi = m; }
    float cnt = (float)(lo - s);

    __shared__ float sg[HID];
    __shared__ float r0[HID], r1[HID];
    sg[c] = gsum[gr * HID + c] / fmaxf(cnt, 1.0f) + loadf(b2, c, ff);
    __syncthreads();
    float acc = loadf(bm1, c, ff);
#pragma unroll 8
    for (int k = 0; k < HID; k++) acc += sg[k] * loadf(Wm1, k * HID + c, ff);
    float hid = fmaxf(acc, 0.f);
    r0[c] = hid * loadf(Wm2, c * OUT_C + 0, ff);
    r1[c] = hid * loadf(Wm2, c * OUT_C + 1, ff);
    __syncthreads();
    for (int off = 64; off > 0; off >>= 1) {
        if (c < off) { r0[c] += r0[c + off]; r1[c] += r1[c + off]; }
        __syncthreads();
    }
    if (c == 0) {
        out[gr * OUT_C + 0] = r0[0] + loadf(bm2, 0, ff);
        out[gr * OUT_C + 1] = r1[0] + loadf(bm2, 1, ff);
    }
}

// ---------------- launch ----------------

extern "C" void kernel_launch(void* const* d_in, const int* in_sizes, int n_in,
                              void* d_out, int out_size, void* d_ws, size_t ws_size,
                              hipStream_t stream) {
    const void* x     = d_in[0];
    const void* ei    = d_in[1];
    const void* batch = d_in[2];
    const void* W1  = d_in[3];
    const void* b1  = d_in[4];
    const void* W2  = d_in[5];
    const void* b2  = d_in[6];
    const void* Wm1 = d_in[7];
    const void* bm1 = d_in[8];
    const void* Wm2 = d_in[9];
    const void* bm2 = d_in[10];

    char* p = (char*)d_ws;
    auto alloc = [&](size_t bytes) {
        char* r = p;
        p += (bytes + 255) & ~(size_t)255;
        return r;
    };
    int*    iflag  = (int*)alloc(4);
    int*    fflag  = (int*)alloc(4);
    int*    bcnt   = (int*)alloc(NBUCK * 4);
    uint2*  bmem   = (uint2*)alloc((size_t)NBUCK * BCAP * 8);
    float*  dinv   = (float*)alloc(N_NODES * 4);
    int*    offs   = (int*)alloc((N_NODES + 1) * 4);
    int*    csr    = (int*)alloc(N_EDGES * 4);
    ushort* Wt1    = (ushort*)alloc(IN_C * HID * 2);
    ushort* Wt2    = (ushort*)alloc(HID * HID * 2);
    ushort* Y1     = (ushort*)alloc((size_t)N_NODES * IN_C * 2);
    ushort* Mbuf   = (ushort*)alloc((size_t)N_NODES * IN_C * 2);
    ushort* h1s    = (ushort*)alloc((size_t)N_NODES * HID * 2);
    ushort* N2     = (ushort*)alloc((size_t)N_NODES * HID * 2);
    float*  gbuf   = (float*)alloc(N_GRAPHS * HID * 4);

    k_init<<<(N_GRAPHS * HID + 255) / 256, 256, 0, stream>>>(
        (const uint*)batch, (const uint*)x, bcnt, gbuf, iflag, fflag);
    k_binA<<<(N_EDGES + ECH - 1) / ECH, 1024, 0, stream>>>(
        ei, iflag, fflag, W1, W2, Wt1, Wt2, bcnt, bmem);
    k_binB<<<NBUCK, 1024, 0, stream>>>(bmem, bcnt, x, fflag, offs, csr, dinv, Y1);

    // layer 1 (aggregate-first): M = dinv*(gather Y1 + self); h1s = relu(M@W1+b1)*dinv
    k_aggM<<<(N_NODES * 8 + 255) / 256, 256, 0, stream>>>(Y1, dinv, offs, csr, Mbuf);
    k_gemm_f<IN_C><<<(N_NODES + 63) / 64, 256, 0, stream>>>(Mbuf, Wt1, fflag, dinv, b1, h1s);
    // layer 2: N2 = dinv*(gather h1s + self); pool(N2@W2) fused
    k_agg128<<<(N_NODES * 16 + 255) / 256, 256, 0, stream>>>(h1s, dinv, offs, csr, N2);
    k_gemm_pool<<<(N_NODES + 63) / 64, 256, 0, stream>>>(N2, Wt2, batch, iflag, gbuf);

    k_mlp<<<N_GRAPHS, HID, 0, stream>>>(gbuf, batch, iflag, b2, Wm1, bm1, Wm2, bm2, fflag, (float*)d_out);
}